// Round 13
// baseline (20800.293 us; speedup 1.0000x reference)
//
#include <hip/hip_runtime.h>
#include <math.h>

#define NV 50000
#define NB 2048
#define NKEEP 65          // K+1
#define RADIUS_F 0.2f

#define TPB 1024          // FPS threads (single block)
#define PPT 49            // points per thread; 1024*49 = 50176 >= 50000
#define NPAD (TPB * PPT)

#define NCELL 4096        // 16^3 Morton cells

#define ROW_THR 256
#define CAP 5120          // all-in-radius candidate buffer per row (LDS)
#define CAP2 512          // sub-compacted (b<=kbin) buffer

// ---------------- no-contract arithmetic helpers ----------------

static __device__ __forceinline__ float sn_nc(float x, float y, float z) {
#pragma clang fp contract(off)
  return (x * x + y * y) + z * z;
}

static __device__ __forceinline__ float d2_nc(float ax, float ay, float az,
                                              float bx, float by, float bz) {
#pragma clang fp contract(off)
  float dx = ax - bx, dy = ay - by, dz = az - bz;
  return (dx * dx + dy * dy) + dz * dz;
}

static __device__ __forceinline__ float tval_nc(float cx, float cy, float cz,
                                                float px, float py, float pz,
                                                float pw) {
#pragma clang fp contract(off)
  float gd = (cx * px + cy * py) + cz * pz;
  return (pw - 2.0f * gd) + pw;
}

// ---------------- helpers ----------------

static __device__ __forceinline__ unsigned spread3(unsigned v) {
  // 4-bit value -> bits at positions 0,3,6,9
  return (v & 1u) | ((v & 2u) << 2) | ((v & 4u) << 4) | ((v & 8u) << 6);
}

static __device__ __forceinline__ unsigned cell_of(float x, float y, float z) {
  int ix = (int)(x * 16.0f); ix = ix < 0 ? 0 : (ix > 15 ? 15 : ix);
  int iy = (int)(y * 16.0f); iy = iy < 0 ? 0 : (iy > 15 ? 15 : iy);
  int iz = (int)(z * 16.0f); iz = iz < 0 ? 0 : (iz > 15 ? 15 : iz);
  return (spread3((unsigned)ix) << 2) | (spread3((unsigned)iy) << 1) | spread3((unsigned)iz);
}

// ---------------- kernel A: zero histogram ----------------

__global__ void k_zero(unsigned* __restrict__ hist) {
  int i = blockIdx.x * blockDim.x + threadIdx.x;
  if (i < NCELL) hist[i] = 0u;
}

// ---------------- kernel B: pack pts + cell histogram + cidx[0] ----------------

__global__ void k_prep(const float* __restrict__ vtx, float4* __restrict__ pts,
                       int* __restrict__ cidx, unsigned* __restrict__ hist) {
  int i = blockIdx.x * blockDim.x + threadIdx.x;
  if (i < NV) {
    float x = vtx[3 * i], y = vtx[3 * i + 1], z = vtx[3 * i + 2];
    pts[i] = make_float4(x, y, z, sn_nc(x, y, z));
    atomicAdd(&hist[cell_of(x, y, z)], 1u);
  }
  if (i == 0) cidx[0] = 0;
}

// ---------------- kernel C: exclusive scan over 4096 cells (1 block) ----------------

__global__ __launch_bounds__(1024)
void k_scan(unsigned* __restrict__ hist) {
  __shared__ unsigned sh[NCELL];
  __shared__ unsigned ss[1024];
  const int t = threadIdx.x;
  for (int j = t; j < NCELL; j += 1024) sh[j] = hist[j];
  __syncthreads();
  const unsigned c0 = sh[4 * t], c1 = sh[4 * t + 1], c2 = sh[4 * t + 2], c3 = sh[4 * t + 3];
  const unsigned s = c0 + c1 + c2 + c3;
  ss[t] = s;
  __syncthreads();
  for (int off = 1; off < 1024; off <<= 1) {          // inclusive Hillis-Steele
    const unsigned v = (t >= off) ? ss[t - off] : 0u;
    __syncthreads();
    ss[t] += v;
    __syncthreads();
  }
  const unsigned excl = ss[t] - s;
  hist[4 * t] = excl;
  hist[4 * t + 1] = excl + c0;
  hist[4 * t + 2] = excl + c0 + c1;
  hist[4 * t + 3] = excl + c0 + c1 + c2;
}

// ---------------- kernel D: scatter into Morton order ----------------

__global__ void k_scatter(const float* __restrict__ vtx, float4* __restrict__ spts,
                          unsigned* __restrict__ hist) {
  int i = blockIdx.x * blockDim.x + threadIdx.x;
  if (i < NV) {
    float x = vtx[3 * i], y = vtx[3 * i + 1], z = vtx[3 * i + 2];
    const unsigned pos = atomicAdd(&hist[cell_of(x, y, z)], 1u);
    spts[pos] = make_float4(x, y, z, __uint_as_float((unsigned)i));  // .w = orig idx bits
  }
}

// ---------------- kernel E: FPS — single block, bbox-pruned, 2 barriers/step ----------------

__global__ __launch_bounds__(TPB, 1)
void k_fps(const float4* __restrict__ pts, const float4* __restrict__ spts,
           int* __restrict__ cidx) {
  const int tid = threadIdx.x;
  const int lane = tid & 63;
  const int wid = tid >> 6;
  const int sbase = tid * PPT;

  __shared__ unsigned long long s_key[TPB];
  __shared__ float s_cx[TPB], s_cy[TPB], s_cz[TPB];
  __shared__ float s_wx, s_wy, s_wz;

  // per-point min-dist state (registers, statically indexed via full unroll)
  float m[PPT];
  float mnx = 1e30f, mny = 1e30f, mnz = 1e30f, mxx = -1e30f, mxy = -1e30f, mxz = -1e30f;
  unsigned long long bkey = 0ull;
  float bm = 0.f, bx = 0.f, by = 0.f, bz = 0.f;
  {
    const float4 seed = pts[0];                        // original point 0
#pragma unroll
    for (int k = 0; k < PPT; ++k) {
      const int g = sbase + k;
      const float4 p = spts[g];                        // tail slots: poison coords, handled below
      const bool real = g < NV;
      const float d2 = d2_nc(p.x, p.y, p.z, seed.x, seed.y, seed.z);
      m[k] = real ? d2 : 0.f;                          // dummy m=0: key=0, never wins
      mnx = fminf(mnx, p.x); mny = fminf(mny, p.y); mnz = fminf(mnz, p.z);
      mxx = fmaxf(mxx, p.x); mxy = fmaxf(mxy, p.y); mxz = fmaxf(mxz, p.z);
      const unsigned orig = real ? __float_as_uint(p.w) : 0xFFFFu;
      const unsigned long long key =
          ((unsigned long long)__float_as_uint(m[k]) << 16) |
          (unsigned long long)(0xFFFFu - (orig & 0xFFFFu));
      if (key > bkey) { bkey = key; bm = m[k]; bx = p.x; by = p.y; bz = p.z; }
    }
  }
  const float bcx = 0.5f * (mnx + mxx);
  const float bcy = 0.5f * (mny + mxy);
  const float bcz = 0.5f * (mnz + mxz);
  const float br = sqrtf(0.25f * ((mxx - mnx) * (mxx - mnx) +
                                  (mxy - mny) * (mxy - mny) +
                                  (mxz - mnz) * (mxz - mnz)));

  for (int t = 0; t < NB - 1; ++t) {
    // ---- publish local best to LDS ----
    s_key[tid] = bkey;
    s_cx[tid] = bx; s_cy[tid] = by; s_cz[tid] = bz;
    __syncthreads();                                   // SYNC_A

    // ---- wave 0: global argmax over 1024 keys (16/lane scan + 6-lvl shfl) ----
    if (wid == 0) {
      unsigned long long kk = 0ull; int kt = 0;
#pragma unroll
      for (int j = 0; j < 16; ++j) {
        const int idx = lane + 64 * j;
        const unsigned long long c = s_key[idx];
        if (c > kk) { kk = c; kt = idx; }
      }
#pragma unroll
      for (int sh = 1; sh < 64; sh <<= 1) {
        const unsigned long long ok = __shfl_xor(kk, sh, 64);
        const int ot = __shfl_xor(kt, sh, 64);
        if (ok > kk) { kk = ok; kt = ot; }
      }
      if (lane == 0) {
        s_wx = s_cx[kt]; s_wy = s_cy[kt]; s_wz = s_cz[kt];
        cidx[t + 1] = (int)(0xFFFFu - (unsigned)(kk & 0xFFFFull));
      }
    }
    __syncthreads();                                   // SYNC_B

    // ---- bbox-pruned update + argmax rebuild ----
    const float wx = s_wx, wy = s_wy, wz = s_wz;
    const float ddx = wx - bcx, ddy = wy - bcy, ddz = wz - bcz;
    const float dwc = sqrtf(ddx * ddx + ddy * ddy + ddz * ddz);
    // skip is exact: dist(p,w) >= dwc - br > sqrt(bm) + margin >= sqrt(m[k]) + margin
    // (margin 1e-4 >> fp error ~1e-5) -> fminf leaves every m[k] bit-identical
    if (dwc <= br + sqrtf(bm) + 1e-4f) {
      bkey = 0ull; bm = 0.f; bx = 0.f; by = 0.f; bz = 0.f;
#pragma unroll
      for (int k = 0; k < PPT; ++k) {
        const int g = sbase + k;
        const float4 p = spts[g];
        const float nd = d2_nc(p.x, p.y, p.z, wx, wy, wz);
        m[k] = fminf(m[k], nd);                        // dummy: min(0,nd)=0 stays 0
        const unsigned orig = (g < NV) ? __float_as_uint(p.w) : 0xFFFFu;
        const unsigned long long key =
            ((unsigned long long)__float_as_uint(m[k]) << 16) |
            (unsigned long long)(0xFFFFu - (orig & 0xFFFFu));
        if (key > bkey) { bkey = key; bm = m[k]; bx = p.x; by = p.y; bz = p.z; }
      }
    }
  }
}

// ---------------- kernel F: per-centroid select + MLP + aggregate + global ----------------

__global__ __launch_bounds__(ROW_THR, 3)
void k_row(const float4* __restrict__ pts, const int* __restrict__ cidx,
           const float* __restrict__ W1, const float* __restrict__ b1,
           const float* __restrict__ W2, const float* __restrict__ b2,
           const float* __restrict__ Wg, const float* __restrict__ bg,
           float* __restrict__ out) {
  const int tid = threadIdx.x;
  const int row = blockIdx.x;

  __shared__ unsigned hist[1024];
  __shared__ unsigned psum[ROW_THR];
  __shared__ float cd[CAP];
  __shared__ int cidb[CAP];
  __shared__ float cd2[CAP2];
  __shared__ int ci2[CAP2];
  __shared__ int vlist[NKEEP];
  __shared__ float s_h[4][64];
  __shared__ float s_mred[4][64];
  __shared__ float s_agg[64];
  __shared__ int s_validn, s_k, s_mode, s_ncand, s_n2;

  const float4 c4 = pts[cidx[row]];

  for (int i = tid; i < 1024; i += ROW_THR) hist[i] = 0u;
  if (tid == 0) { s_ncand = 0; s_n2 = 0; }
  __syncthreads();

  // single global pass: compact ALL in-radius candidates + histogram
  for (int j = tid; j < NV; j += ROW_THR) {
    const float4 p = pts[j];
    const float t = tval_nc(c4.x, c4.y, c4.z, p.x, p.y, p.z, p.w);
    const float at = fabsf(t);
    if (at <= 0.0402f) {                 // conservative prefilter: d > 0.2004 otherwise
      const float d = sqrtf(at);
      if (d <= RADIUS_F) {
        const int pos = atomicAdd(&s_ncand, 1);
        if (pos < CAP) { cd[pos] = d; cidb[pos] = j; }
        int b = (int)(d * 5120.0f); if (b > 1023) b = 1023;
        atomicAdd(&hist[b], 1u);
      }
    }
  }
  __syncthreads();
  int n = s_ncand; if (n > CAP) n = CAP;

  {
    const int base = tid * 4;
    psum[tid] = hist[base] + hist[base + 1] + hist[base + 2] + hist[base + 3];
  }
  __syncthreads();
  if (tid == 0) {
    if (s_ncand <= NKEEP) {
      s_mode = 0; s_k = 1023;            // all in-radius points are valid
    } else {
      int cum = 0, kk = 1023;
      for (int i = 0; i < ROW_THR; ++i) {
        const int nc = cum + (int)psum[i];
        if (nc >= NKEEP) {
          int c2 = cum;
          for (int b = 0; b < 4; ++b) {
            c2 += (int)hist[i * 4 + b];
            if (c2 >= NKEEP) { kk = i * 4 + b; break; }
          }
          break;
        }
        cum = nc;
      }
      s_mode = 1; s_k = kk;
    }
  }
  __syncthreads();
  const int mode = s_mode, kbin = s_k;

  if (mode == 0) {
    if (tid < n) vlist[tid] = cidb[tid];       // n <= 65, all valid (max-agg is order-free)
    if (tid == 0) s_validn = n;
  } else {
    // sub-compact candidates with bin <= kbin from the LDS list (no global re-scan)
    for (int c = tid; c < n; c += ROW_THR) {
      const float d = cd[c];
      int b = (int)(d * 5120.0f); if (b > 1023) b = 1023;
      if (b <= kbin) {
        const int p = atomicAdd(&s_n2, 1);
        if (p < CAP2) { cd2[p] = d; ci2[p] = cidb[c]; }
      }
    }
    __syncthreads();
    int n2 = s_n2; if (n2 > CAP2) n2 = CAP2;
    // exact 65 smallest by (d, idx) lexicographic (matches lax.top_k tie-break)
    for (int c = tid; c < n2; c += ROW_THR) {
      const float dc = cd2[c]; const int ic = ci2[c];
      int r = 0;
      for (int j2 = 0; j2 < n2; ++j2) {
        const float dj = cd2[j2]; const int ij = ci2[j2];
        r += (int)((dj < dc) | ((dj == dc) & (ij < ic)));
      }
      if (r < NKEEP) vlist[r] = ic;
    }
    if (tid == 0) s_validn = NKEEP;
  }
  __syncthreads();
  const int nvld = s_validn;

  // MLP: 4 neighbor-groups x 64 channels
  const int ch = tid & 63, grp = tid >> 6;
  float amax = -INFINITY;
  for (int base = 0; base < nvld; base += 4) {
    const int slot = base + grp;
    if (slot < nvld) {
      const int j = vlist[slot];
      const float4 p = pts[j];
      const float f3 = p.x - c4.x, f4 = p.y - c4.y, f5 = p.z - c4.z;
      float hs = p.x * W1[ch] + p.y * W1[64 + ch] + p.z * W1[128 + ch]
               + f3 * W1[192 + ch] + f4 * W1[256 + ch] + f5 * W1[320 + ch];
      hs += b1[ch];
      s_h[grp][ch] = fmaxf(hs, 0.f);
    }
    __syncthreads();
    if (slot < nvld) {
      float acc = 0.f;
#pragma unroll 8
      for (int k2 = 0; k2 < 64; ++k2) acc += s_h[grp][k2] * W2[k2 * 64 + ch];
      acc += b2[ch];
      amax = fmaxf(amax, acc);
    }
    __syncthreads();
  }
  s_mred[grp][ch] = amax;
  __syncthreads();
  if (tid < 64) {
    s_agg[tid] = fmaxf(fmaxf(s_mred[0][tid], s_mred[1][tid]),
                       fmaxf(s_mred[2][tid], s_mred[3][tid]));
  }
  __syncthreads();
  if (tid < 128) {
    float acc = 0.f;
#pragma unroll 8
    for (int k2 = 0; k2 < 64; ++k2) acc += s_agg[k2] * Wg[k2 * 128 + tid];
    out[row * 128 + tid] = acc + bg[tid];
  }
}

// ---------------- launch ----------------

extern "C" void kernel_launch(void* const* d_in, const int* in_sizes, int n_in,
                              void* d_out, int out_size, void* d_ws, size_t ws_size,
                              hipStream_t stream) {
  const float* vtx = (const float*)d_in[0];
  const float* W1  = (const float*)d_in[1];
  const float* b1  = (const float*)d_in[2];
  const float* W2  = (const float*)d_in[3];
  const float* b2  = (const float*)d_in[4];
  const float* Wg  = (const float*)d_in[5];
  const float* bg  = (const float*)d_in[6];
  float* out = (float*)d_out;

  char* ws = (char*)d_ws;
  float4* pts = (float4*)ws;                               // 800,000 B
  int* cidx = (int*)(ws + 800000);                         // 8,192 B
  float4* spts = (float4*)(ws + 808192);                   // 802,816 B (NPAD*16)
  unsigned* hist = (unsigned*)(ws + 1611008);              // 16,384 B  -> total 1,627,392 B

  k_zero<<<dim3((NCELL + 255) / 256), dim3(256), 0, stream>>>(hist);
  k_prep<<<dim3((NV + 255) / 256), dim3(256), 0, stream>>>(vtx, pts, cidx, hist);
  k_scan<<<dim3(1), dim3(1024), 0, stream>>>(hist);
  k_scatter<<<dim3((NV + 255) / 256), dim3(256), 0, stream>>>(vtx, spts, hist);
  k_fps<<<dim3(1), dim3(TPB), 0, stream>>>(pts, spts, cidx);
  k_row<<<dim3(NB), dim3(ROW_THR), 0, stream>>>(pts, cidx, W1, b1, W2, b2, Wg, bg, out);
}